// Round 16
// baseline (364.541 us; speedup 1.0000x reference)
//
#include <hip/hip_runtime.h>
#include <hip/hip_bf16.h>

typedef __attribute__((ext_vector_type(8))) short short8;
typedef __attribute__((ext_vector_type(4))) float floatx4;
typedef __attribute__((ext_vector_type(4))) unsigned int uintx4;

#define D_MODEL 1024
#define T_SEQ   2048
#define N_HEAD  16
#define NEG_BIG (-1e30f)
#define LDSP 40 // fallback-gemm pitch
#define VP 72   // V-tile pitch: 144B rows, 16B-aligned -> true ds_read_b128
#define PP 72   // P-tile pitch
#define RESCALE_THR 8.0f  // T13 defer-max threshold (P bounded by e^8)

static __device__ __forceinline__ float bf2f(ushort u) {
  unsigned int x = ((unsigned int)u) << 16;
  return __builtin_bit_cast(float, x);
}
static __device__ __forceinline__ ushort san(ushort u) {
  return ((u & 0x7F80u) == 0x7F80u) ? (ushort)0 : u;
}
static __device__ __forceinline__ float bf2f_s(ushort u) { return bf2f(san(u)); }
static __device__ __forceinline__ ushort f2bf(float f) {
  unsigned int x = __builtin_bit_cast(unsigned int, f);
  x += 0x7FFFu + ((x >> 16) & 1u);
  return (ushort)(x >> 16);
}
static __device__ __forceinline__ float ext_ld(const void* p, size_t i, int isbf) {
  return isbf ? bf2f_s(((const ushort*)p)[i]) : ((const float*)p)[i];
}
// exact bf16 *0.125: decrement exponent by 3 (power-of-2 -> lossless).
static __device__ __forceinline__ short8 qscale8(short8 v) {
  short8 o;
#pragma unroll
  for (int i = 0; i < 8; i++) {
    ushort u = (ushort)v[i];
    int e = (u >> 7) & 0xFF;
    o[i] = (short)((e > 3) ? (ushort)(u - (3 << 7)) : (ushort)(u & 0x8000u));
  }
  return o;
}
// async global->LDS DMA, 16 B/lane; LDS dest = wave-uniform base + lane*16
static __device__ __forceinline__ void gload16(const void* g, void* l) {
  __builtin_amdgcn_global_load_lds(
      (const __attribute__((address_space(1))) void*)g,
      (__attribute__((address_space(3))) void*)l, 16, 0, 0);
}
// block barrier WITHOUT vmcnt drain (r12: attn 99.3->98.0us vs __syncthreads)
static __device__ __forceinline__ void barrier_lds_only() {
  asm volatile("s_waitcnt lgkmcnt(0)" ::: "memory");
  __builtin_amdgcn_s_barrier();
  __builtin_amdgcn_sched_barrier(0);
}

// wave-autonomous LayerNorm row: one WAVE owns one row (16 elems/lane,
// 6-shuffle reduce) -- no LDS, no block barriers (r16; was 2 barriers/row).
static __device__ __forceinline__ void ln_row(
    const void* __restrict__ x, const void* __restrict__ g,
    const void* __restrict__ bb, ushort* __restrict__ out,
    int row, int lane, int xbf, int wbf) {
  size_t ro = (size_t)row * D_MODEL;
  float v[16], gv[16], bv[16];
  if (!xbf) {
    const float* xf = (const float*)x + ro + lane * 16;
#pragma unroll
    for (int i = 0; i < 4; i++) {
      floatx4 t = *(const floatx4*)(xf + i * 4);
#pragma unroll
      for (int j = 0; j < 4; j++) v[i * 4 + j] = t[j];
    }
  } else {
    const ushort* xu = (const ushort*)x + ro + lane * 16;
    ushort tmp[16] __attribute__((aligned(16)));
    *(uintx4*)tmp = *(const uintx4*)xu;
    *(uintx4*)(tmp + 8) = *(const uintx4*)(xu + 8);
#pragma unroll
    for (int i = 0; i < 16; i++) v[i] = bf2f_s(tmp[i]);
  }
  float s = 0.f, sq = 0.f;
#pragma unroll
  for (int i = 0; i < 16; i++) { s += v[i]; sq += v[i] * v[i]; }
#pragma unroll
  for (int d = 32; d; d >>= 1) {
    s += __shfl_xor(s, d, 64);
    sq += __shfl_xor(sq, d, 64);
  }
  float mu = s * (1.0f / D_MODEL);
  float var = sq * (1.0f / D_MODEL) - mu * mu;
  float rs = rsqrtf(fmaxf(var, 0.f) + 1e-5f);
  if (!wbf) {
    const float* gf = (const float*)g + lane * 16;
    const float* bf = (const float*)bb + lane * 16;
#pragma unroll
    for (int i = 0; i < 4; i++) {
      floatx4 gt = *(const floatx4*)(gf + i * 4);
      floatx4 bt = *(const floatx4*)(bf + i * 4);
#pragma unroll
      for (int j = 0; j < 4; j++) { gv[i * 4 + j] = gt[j]; bv[i * 4 + j] = bt[j]; }
    }
  } else {
    const ushort* gu = (const ushort*)g + lane * 16;
    const ushort* bu = (const ushort*)bb + lane * 16;
    ushort tg[16] __attribute__((aligned(16)));
    ushort tb[16] __attribute__((aligned(16)));
    *(uintx4*)tg = *(const uintx4*)gu;
    *(uintx4*)(tg + 8) = *(const uintx4*)(gu + 8);
    *(uintx4*)tb = *(const uintx4*)bu;
    *(uintx4*)(tb + 8) = *(const uintx4*)(bu + 8);
#pragma unroll
    for (int i = 0; i < 16; i++) { gv[i] = bf2f_s(tg[i]); bv[i] = bf2f_s(tb[i]); }
  }
  ushort o16[16] __attribute__((aligned(16)));
#pragma unroll
  for (int i = 0; i < 16; i++) o16[i] = f2bf((v[i] - mu) * rs * gv[i] + bv[i]);
  ushort* op = out + ro + lane * 16;
  *(uintx4*)op = *(uintx4*)o16;
  *(uintx4*)(op + 8) = *(uintx4*)(o16 + 8);
}

// dtype probe: low ushort of dword -> bf16 data has exp in [0x60,0x8F] ~100%
// (kept for the fallback path; fast path computes the flag inline)
__global__ void detect_dtype(const ushort* x, uint* flag) {
  int tid = threadIdx.x;
  int cnt = 0;
  for (int j = 0; j < 16; j++) {
    ushort u = x[2 * (tid * 16 + j)];
    int e = (u >> 7) & 0xFF;
    if (e >= 0x60 && e <= 0x8F) cnt++;
  }
  for (int d = 32; d; d >>= 1) cnt += __shfl_xor(cnt, d, 64);
  __shared__ int c[4];
  if ((tid & 63) == 0) c[tid >> 6] = cnt;
  __syncthreads();
  if (tid == 0) flag[0] = (c[0] + c[1] + c[2] + c[3] >= 2048) ? 1u : 0u;
}

// prep_all: inline dtype probe (kills the serialized 1-block detect launch)
// + weight transpose 64x64 tiles (blocks 0..2047) + LN1 one-wave-per-row
// (blocks 2048..3071, 4 rows/block). Block 0 publishes the flag downstream.
__global__ __launch_bounds__(256) void prep_all(
    const void* __restrict__ Wq, const void* __restrict__ Wk,
    const void* __restrict__ Wv, const void* __restrict__ Wo,
    const void* __restrict__ W1, const void* __restrict__ W2,
    ushort* __restrict__ oq, ushort* __restrict__ ok, ushort* __restrict__ ov,
    ushort* __restrict__ oo, ushort* __restrict__ o1, ushort* __restrict__ o2,
    const void* __restrict__ x, const void* __restrict__ ln_g,
    const void* __restrict__ ln_b, ushort* __restrict__ ln_out,
    uint* __restrict__ flagp) {
  int id = blockIdx.x;
  int tid = threadIdx.x;

  // ---- inline dtype probe (all blocks; 16KB region is L2-broadcast-hot) ---
  int cnt = 0;
  {
    const ushort* xu = (const ushort*)x;
    for (int j = 0; j < 16; j++) {
      ushort u = xu[2 * (tid * 16 + j)];
      int e = (u >> 7) & 0xFF;
      if (e >= 0x60 && e <= 0x8F) cnt++;
    }
    for (int d = 32; d; d >>= 1) cnt += __shfl_xor(cnt, d, 64);
  }
  __shared__ int c[4];
  if ((tid & 63) == 0) c[tid >> 6] = cnt;
  __syncthreads();
  int isbf = (c[0] + c[1] + c[2] + c[3] >= 2048) ? 1 : 0;
  if (id == 0 && tid == 0) flagp[0] = (uint)isbf;

  if (id >= 2048) {
    // ---- LN1: one wave per row (input dtype follows flag) ----
    int row = (id - 2048) * 4 + (tid >> 6);
    ln_row(x, ln_g, ln_b, ln_out, row, tid & 63, isbf, isbf);
    return;
  }

  // ---- weight convert+transpose tile (64x64) ----
  const void* in;
  ushort* out;
  int R, C, local;
  if (id < 1024) {
    int w = id >> 8;
    local = id & 255;
    R = 1024; C = 1024;
    in  = (w == 0) ? Wq : (w == 1) ? Wk : (w == 2) ? Wv : Wo;
    out = (w == 0) ? oq : (w == 1) ? ok : (w == 2) ? ov : oo;
  } else if (id < 1536) {
    local = id - 1024; R = 1024; C = 2048; in = W1; out = o1;
  } else {
    local = id - 1536; R = 2048; C = 1024; in = W2; out = o2;
  }
  int cb = C >> 6;
  int c0 = (local % cb) * 64, r0 = (local / cb) * 64;
  __shared__ float t[64][65];
  int cc = tid & 63, ty = tid >> 6;
  for (int rr = ty; rr < 64; rr += 4)
    t[rr][cc] = ext_ld(in, (size_t)(r0 + rr) * C + c0 + cc, isbf);
  __syncthreads();
  for (int i = ty; i < 64; i += 4)
    out[(size_t)(c0 + i) * R + r0 + cc] = f2bf(t[cc][i]);
}

// ---------------- LayerNorm -> bf16 (wave-per-row; grid = rows/4) ----------
__global__ __launch_bounds__(256) void ln_kernel(
    const void* __restrict__ x, const void* __restrict__ g,
    const void* __restrict__ bb, ushort* __restrict__ out,
    int ext, const uint* __restrict__ flagp) {
  int wbf = (int)*flagp;
  int xbf = ext ? wbf : 1;
  int row = blockIdx.x * 4 + (threadIdx.x >> 6);
  ln_row(x, g, bb, out, row, threadIdx.x & 63, xbf, wbf);
}

// ---------------- fast GEMM: C = A[M,K] @ Bt[N,K]^T, both bf16 --------------
// EPI: 0 plain bf16 | 1 +res(ext) bf16 | 2 +bias(ext)+GELU bf16 |
//      5 +bias(ext)+res(bf16) -> store FINAL dtype
// NT: QKV=128@3/CU (r10: NT=64@6/CU regressed). Wo/FF1/FF2=64 (r4/r12).
// KSTEP=32 (r8's 64 regressed, m132-class).
template <int EPI, int SPLIT, int NT, int KSTEP>
__global__ __launch_bounds__(256) void gemm_tt(
    const ushort* __restrict__ A, int lda,
    const ushort* __restrict__ Bt, int ldbt,
    void* __restrict__ C0v, ushort* __restrict__ C1, ushort* __restrict__ C2,
    int ldc,
    const void* __restrict__ bias, size_t biasoff,
    const void* __restrict__ res, int ldr,
    int M, int K, const uint* __restrict__ flagp) {
  __shared__ __align__(16) ushort As[128 * KSTEP];
  __shared__ __align__(16) ushort Bs[NT * KSTEP];
  int isbf = (int)*flagp;
  int tid = threadIdx.x;
  int wave = tid >> 6, lane = tid & 63, lm = lane & 15, quad = lane >> 4;
  int m0 = blockIdx.x * 128, n0 = blockIdx.y * NT;
  constexpr int MR = (NT == 128) ? 4 : 2;
  constexpr int RPW = 512 / KSTEP;   // rows per wave-DMA
  constexpr int RPC = 4 * RPW;       // rows per gload16 call (4 waves)
  constexpr int LPR = KSTEP / 8;     // lanes per row
  int wm = (NT == 128) ? (wave >> 1) * 64 : wave * 32;
  int wn = (NT == 128) ? (wave & 1) * 64 : 0;
  floatx4 acc[MR][4] = {};
  int srl = lane / LPR;
  int scl = (lane % LPR) * 8;

  for (int kk = 0; kk < K; kk += KSTEP) {
#pragma unroll
    for (int i = 0; i < 128 / RPC; i++)
      gload16(A + (size_t)(m0 + i * RPC + wave * RPW + srl) * lda + kk + scl,
              &As[(i * RPC + wave * RPW) * KSTEP]);
#pragma unroll
    for (int i = 0; i < NT / RPC; i++)
      gload16(Bt + (size_t)(n0 + i * RPC + wave * RPW + srl) * ldbt + kk + scl,
              &Bs[(i * RPC + wave * RPW) * KSTEP]);
    __syncthreads();
#pragma unroll
    for (int kk2 = 0; kk2 < KSTEP; kk2 += 32) {
      short8 af[MR], bf[4];
#pragma unroll
      for (int i = 0; i < MR; i++)
        af[i] = *(const short8*)&As[(wm + i * 16 + lm) * KSTEP + kk2 + quad * 8];
#pragma unroll
      for (int i = 0; i < 4; i++)
        bf[i] = *(const short8*)&Bs[(wn + i * 16 + lm) * KSTEP + kk2 + quad * 8];
#pragma unroll
      for (int mi = 0; mi < MR; mi++)
#pragma unroll
        for (int ni = 0; ni < 4; ni++)
          acc[mi][ni] = __builtin_amdgcn_mfma_f32_16x16x32_bf16(
              af[mi], bf[ni], acc[mi][ni], 0, 0, 0);
    }
    __syncthreads();
  }

  ushort* Cseg = (ushort*)C0v;
  int colbase = n0;
  if (SPLIT) {
    int seg = n0 >> 10;
    Cseg = (seg == 0) ? (ushort*)C0v : (seg == 1 ? C1 : C2);
    colbase = n0 & 1023;
  }
#pragma unroll
  for (int mi = 0; mi < MR; mi++) {
#pragma unroll
    for (int ni = 0; ni < 4; ni++) {
      int col = colbase + wn + ni * 16 + lm;
#pragma unroll
      for (int r = 0; r < 4; r++) {
        int row = m0 + wm + mi * 16 + quad * 4 + r;
        size_t ci = (size_t)row * ldc + col;
        float v = acc[mi][ni][r];
        if (EPI == 2 || EPI == 5) v += ext_ld(bias, biasoff + col, isbf);
        if (EPI == 1) v += ext_ld(res, (size_t)row * ldr + col, isbf);
        if (EPI == 5) v += bf2f(((const ushort*)res)[(size_t)row * ldr + col]);
        if (EPI == 2) v = 0.5f * v * (1.0f + erff(v * 0.70710678118654752f));
        if (EPI == 5 && !isbf) ((float*)C0v)[ci] = v;
        else                   Cseg[ci] = f2bf(v);
      }
    }
  }
}

// ---------------- fallback GEMM: B in [K,N] external dtype ------------------
template <int EPI, int FINAL>
__global__ __launch_bounds__(256) void gemm_kn(
    const ushort* __restrict__ A, int lda,
    const void* __restrict__ B, int ldb, size_t boff,
    void* __restrict__ C, int ldc,
    const void* __restrict__ bias, size_t biasoff,
    const void* __restrict__ res, int ldr,
    int M, int K, const uint* __restrict__ flagp) {
  __shared__ __align__(16) ushort As[128 * LDSP];
  __shared__ __align__(16) ushort Bs[128 * LDSP];
  int isbf = (int)*flagp;
  int tid = threadIdx.x;
  int wave = tid >> 6, lane = tid & 63, lm = lane & 15, quad = lane >> 4;
  int m0 = blockIdx.x * 128, n0 = blockIdx.y * 128;
  int wm = (wave >> 1) * 64, wn = (wave & 1) * 64;
  floatx4 acc[4][4] = {};
  int sr = tid >> 2;
  int sc = (tid & 3) * 8;
  int bk = tid >> 4;
  int bn8 = (tid & 15) * 8;

  for (int kk = 0; kk < K; kk += 32) {
    uintx4 va0 = *(const uintx4*)(A + (size_t)(m0 + sr) * lda + kk + sc);
    uintx4 va1 = *(const uintx4*)(A + (size_t)(m0 + sr + 64) * lda + kk + sc);
    *(uintx4*)&As[sr * LDSP + sc] = va0;
    *(uintx4*)&As[(sr + 64) * LDSP + sc] = va1;
    if (isbf) {
      const ushort* Bu = (const ushort*)B;
#pragma unroll
      for (int p = 0; p < 2; p++) {
        int krow = bk + p * 16;
        uintx4 raw = *(const uintx4*)(Bu + boff + (size_t)(kk + krow) * ldb + n0 + bn8);
        ushort tmp[8] __attribute__((aligned(16)));
        *(uintx4*)tmp = raw;
#pragma unroll
        for (int i = 0; i < 8; i++) Bs[(bn8 + i) * LDSP + krow] = san(tmp[i]);
      }
    } else {
      const float* Bf = (const float*)B;
#pragma unroll
      for (int p = 0; p < 2; p++) {
        int krow = bk + p * 16;
        const float* src = Bf + boff + (size_t)(kk + krow) * ldb + n0 + bn8;
        floatx4 f0 = *(const floatx4*)src;
        floatx4 f1 = *(const floatx4*)(src + 4);
#pragma unroll
        for (int i = 0; i < 4; i++) {
          Bs[(bn8 + i) * LDSP + krow] = f2bf(f0[i]);
          Bs[(bn8 + 4 + i) * LDSP + krow] = f2bf(f1[i]);
        }
      }
    }
    __syncthreads();
    short8 af[4], bf[4];
#pragma unroll
    for (int i = 0; i < 4; i++)
      af[i] = *(const short8*)&As[(wm + i * 16 + lm) * LDSP + quad * 8];
#pragma unroll
    for (int i = 0; i < 4; i++)
      bf[i] = *(const short8*)&Bs[(wn + i * 16 + lm) * LDSP + quad * 8];
#pragma unroll
    for (int mi = 0; mi < 4; mi++)
#pragma unroll
      for (int ni = 0; ni < 4; ni++)
        acc[mi][ni] = __builtin_amdgcn_mfma_f32_16x16x32_bf16(
            af[mi], bf[ni], acc[mi][ni], 0, 0, 0);
    __syncthreads();
  }

#pragma unroll
  for (int mi = 0; mi < 4; mi++) {
#pragma unroll
    for (int ni = 0; ni < 4; ni++) {
      int col = n0 + wn + ni * 16 + lm;
#pragma unroll
      for (int r = 0; r < 4; r++) {
        int row = m0 + wm + mi * 16 + quad * 4 + r;
        size_t ci = (size_t)row * ldc + col;
        float v = acc[mi][ni][r];
        if (EPI == 4)
          v += (FINAL && !isbf) ? ((const float*)C)[ci] : bf2f(((const ushort*)C)[ci]);
        if (EPI == 2 || EPI == 4) v += ext_ld(bias, biasoff + col, isbf);
        if (EPI == 1) v += ext_ld(res, (size_t)row * ldr + col, isbf);
        if (EPI == 4) v += bf2f(((const ushort*)res)[(size_t)row * ldr + col]);
        if (EPI == 2) v = 0.5f * v * (1.0f + erff(v * 0.70710678118654752f));
        if (FINAL && !isbf) ((float*)C)[ci] = v;
        else                ((ushort*)C)[ci] = f2bf(v);
      }
    }
  }
}

// ---------------- causal flash attention (best-known: 90.0us) ---------------
// r15 final: uniform pairing + swapped softmax + qscale + hoisted mask +
// T13 defer-max + barrier_lds_only. DO NOT touch.
__global__ __launch_bounds__(256) void attn_kernel(
    const ushort* __restrict__ q, const ushort* __restrict__ k,
    const ushort* __restrict__ v, ushort* __restrict__ ctx) {
  int tid = threadIdx.x, wave = tid >> 6, lane = tid & 63;
  int lm = lane & 15, quad = lane >> 4;
  int bx = blockIdx.x, h = blockIdx.y, b = blockIdx.z;
  size_t base = (size_t)b * T_SEQ * D_MODEL + h * 64;

  __shared__ __align__(16) ushort Vst[64 * VP];      // [hd][key]
  __shared__ __align__(16) ushort PlAll[4][16 * PP]; // per-wave P
  ushort* Pl = PlAll[wave];

  int vr_r = tid & 63, vcg = (tid >> 6) * 16;
  const ushort* vrow = v + base + vcg;

#pragma unroll
  for (int qsel = 0; qsel < 2; ++qsel) {
    int qt = qsel ? (31 - bx) : bx;
    int qw = qt * 64 + wave * 16;

    short8 aq0 = qscale8(*(const short8*)&q[base + (size_t)(qw + lm) * D_MODEL + quad * 8]);
    short8 aq1 = qscale8(*(const short8*)&q[base + (size_t)(qw + lm) * D_MODEL + 32 + quad * 8]);

    floatx4 O[4] = {};
    float mrq = NEG_BIG, lrq = 0.f;  // running max/denom for query qw+lm

    int ntiles = qt + 1;

    // prefetch tile 0
    uintx4 vv0 = *(const uintx4*)(vrow + (size_t)vr_r * D_MODEL);
    uintx4 vv1 = *(const uintx4*)(vrow + (size_t)vr_r * D_MODEL + 8);
    short8 kfa[4], kfb[4];
#pragma unroll
    for (int g = 0; g < 4; g++) {
      const ushort* kr = &k[base + (size_t)(g * 16 + lm) * D_MODEL + quad * 8];
      kfa[g] = *(const short8*)kr;
      kfb[g] = *(const short8*)(kr + 32);
    }

    for (int kt = 0; kt < ntiles; ++kt) {
      int k0 = kt * 64;
      // scatter prefetched V into shared Vst (all 256 threads)
      {
        ushort t0[8] __attribute__((aligned(16)));
        ushort t1[8] __attribute__((aligned(16)));
        *(uintx4*)t0 = vv0;
        *(uintx4*)t1 = vv1;
#pragma unroll
        for (int i = 0; i < 8; i++) {
          Vst[(vcg + i) * VP + vr_r] = t0[i];
          Vst[(vcg + 8 + i) * VP + vr_r] = t1[i];
        }
      }
      // QK^T SWAPPED: sc[g] = S^T[key=g*16+quad*4+r][query=lm] (pre-scaled)
      floatx4 sc[4];
#pragma unroll
      for (int g = 0; g < 4; g++) {
        floatx4 z = {};
        sc[g] = __builtin_amdgcn_mfma_f32_16x16x32_bf16(kfa[g], aq0, z, 0, 0, 0);
        sc[g] = __builtin_amdgcn_mfma_f32_16x16x32_bf16(kfb[g], aq1, sc[g], 0, 0, 0);
      }
      // issue prefetch for next tile (stays in flight across barriers)
      int k0n = (kt + 1 < ntiles) ? k0 + 64 : k0;
      uintx4 nv0 = *(const uintx4*)(vrow + (size_t)(k0n + vr_r) * D_MODEL);
      uintx4 nv1 = *(const uintx4*)(vrow + (size_t)(k0n + vr_r) * D_MODEL + 8);
      short8 nka[4], nkb[4];
#pragma unroll
      for (int g = 0; g < 4; g++) {
        const ushort* kr = &k[base + (size_t)(k0n + g * 16 + lm) * D_MODEL + quad * 8];
        nka[g] = *(const short8*)kr;
        nkb[g] = *(const short8*)(kr + 32);
      }
      // online softmax: lane owns query qw+lm, 16 keys in-lane.
      bool full = (k0 + 63 <= qw);
      float a[16];
      if (full) {
#pragma unroll
        for (int g = 0; g < 4; g++)
#pragma unroll
          for (int r = 0; r < 4; r++) a[g * 4 + r] = sc[g][r];
      } else {
        int qrow = qw + lm;
#pragma unroll
        for (int g = 0; g < 4; g++)
#pragma unroll
          for (int r = 0; r < 4; r++) {
            float s = sc[g][r];
            if (k0 + g * 16 + quad * 4 + r > qrow) s = NEG_BIG;
            a[g * 4 + r] = s;
          }
      }
      float m0 = fmaxf(fmaxf(a[0], a[1]), fmaxf(a[2], a[3]));
      float m1 = fmaxf(fmaxf(a[4], a[5]), fmaxf(a[6], a[7]));
      float m2 = fmaxf(fmaxf(a[8], a[9]), fmaxf(a[10], a[11]));
      float m3 = fmaxf(fmaxf(a[12], a[13]), fmaxf(a[14], a[15]));
      float lmax = fmaxf(fmaxf(m0, m1), fmaxf(m2, m3));
      // T13 defer-max (mrq replicated across the 4 lanes of each query)
      if (!__all(lmax - mrq <= RESCALE_THR)) {
        float tm = fmaxf(lmax, __shfl_xor(lmax, 16, 64));
        tm = fmaxf(tm, __shfl_xor(tm, 32, 64));
        float mn = fmaxf(mrq, tm);
        float alpha = __expf(mrq - mn);
        mrq = mn;
        lrq *= alpha;
#pragma unroll
        for (int r = 0; r < 4; r++) {
          float aw = __shfl(alpha, quad * 4 + r, 64);
          O[0][r] *= aw; O[1][r] *= aw; O[2][r] *= aw; O[3][r] *= aw;
        }
      }
      float rs0 = 0.f, rs1 = 0.f;
#pragma unroll
      for (int i = 0; i < 8; i++) { a[i] = __expf(a[i] - mrq); rs0 += a[i]; }
#pragma unroll
      for (int i = 8; i < 16; i++) { a[i] = __expf(a[i] - mrq); rs1 += a[i]; }
      float rsum = rs0 + rs1;
      rsum += __shfl_xor(rsum, 16, 64);
      rsum += __shfl_xor(rsum, 32, 64);
      lrq += rsum;
      // P write: lane's 4 consecutive keys per g -> one ds_write_b64
#pragma unroll
      for (int g = 0; g < 4; g++) {
        ushort o4[4] __attribute__((aligned(8)));
#pragma unroll
        for (int r = 0; r < 4; r++) o4[r] = f2bf(a[g * 4 + r]);
        *(uint2*)&Pl[lm * PP + g * 16 + quad * 4] = *(uint2*)o4;
      }
      barrier_lds_only();   // Vst scatter + P stores visible; vmem in flight
      short8 pa0 = *(const short8*)&Pl[lm * PP + quad * 8];
      short8 pa1 = *(const short8*)&Pl[lm * PP + 32 + quad * 8];
#pragma unroll
      for (int d4 = 0; d4 < 4; d4++) {
        short8 bv0 = *(const short8*)&Vst[(d4 * 16 + lm) * VP + quad * 8];
        short8 bv1 = *(const short8*)&Vst[(d4 * 16 + lm) * VP + 32 + quad * 8];
        O[d4] = __builtin_amdgcn_mfma_f32_16x16x32_bf16(pa0, bv0, O[d4], 0, 0, 0);
        O[d4] = __builtin_amdgcn_mfma_f32_16x16x32_bf16(pa1, bv1, O[d4], 0, 0, 0);
      }
      barrier_lds_only();   // all waves' Vst/Pl reads drained (lgkm) -> WAR safe
      vv0 = nv0; vv1 = nv1;
#pragma unroll
      for (int g = 0; g < 4; g++) { kfa[g] = nka[g]; kfb[g] = nkb[g]; }
    }
    float linv = 1.0f / fmaxf(lrq, 1e-20f);
#pragma unroll
    for (int r = 0; r < 4; r++) {
      float lw = __shfl(linv, quad * 4 + r, 64);
#pragma unroll
      for (int d4 = 0; d4 < 4; d4++) {
        ctx[base + (size_t)(qw + quad * 4 + r) * D_MODEL + d4 * 16 + lm] =
            f2bf(O[d4][r] * lw);
      }
    }
  }
}

// ---------------------------------------------------------------------------
extern "C" void kernel_launch(void* const* d_in, const int* in_sizes, int n_in,
                              void* d_out, int out_size, void* d_ws, size_t ws_size,
                              hipStream_t stream) {
  const void* x     = d_in[0];
  const void* ln1_g = d_in[1];
  const void* ln1_b = d_in[2];
  const void* Wq    = d_in[3];
  const void* Wk    = d_in[4];
  const void* Wv    = d_in[5];
  const void* Wo    = d_in[6];
  const void* ln2_g = d_in[7];
  const void* ln2_b = d_in[8];
  const void* W1    = d_in[9];
  const void* b1    = d_in[10];
  const void* W2    = d_in[11];
  const void* b2    = d_in[12];

  const int M = 2 * T_SEQ;  // 4096
  const size_t MEG = 1024 * 1024;
  ushort* W = (ushort*)d_ws;
  ushort* Abuf = W;             // h1 -> ctx -> h2
  ushort* kbuf = W + 4 * MEG;   // k -> x2
  ushort* vbuf = W + 8 * MEG;   // v row-major
  ushort* qbuf = (ushort*)d_out;

  dim3 blk(256);
  dim3 g18(32, 8);
  dim3 attng(T_SEQ / 128, N_HEAD, 2);  // 16 q-tile PAIRS x 16 heads x 2 batch

  bool fast = ws_size >= (size_t)40 * MEG + 4096;

  if (fast) {
    ushort* WqkvT = W + 12 * MEG;             // dead after QKV
    ushort* WoT   = W + 15 * MEG;             // dead after Wo
    ushort* W1T   = W + 16 * MEG;
    ushort* W2T   = W + 18 * MEG;
    ushort* act   = W + 8 * MEG;              // [4096,2048] over v/WqkvT/WoT
    uint* flag = (uint*)(W + 20 * MEG);

    // prep_all computes the dtype flag inline (no serialized detect launch),
    // transposes all weights (64x64 tiles) and runs LN1 wave-per-row.
    prep_all<<<dim3(3072), blk, 0, stream>>>(
        Wq, Wk, Wv, Wo, W1, W2,
        WqkvT, WqkvT + 1 * MEG, WqkvT + 2 * MEG, WoT, W1T, W2T,
        x, ln1_g, ln1_b, Abuf, flag);

    // QKV: 128x128 tile, KSTEP=32 (768 blocks = 3/CU)
    gemm_tt<0, 1, 128, 32><<<dim3(32, 24), blk, 0, stream>>>(
        Abuf, 1024, WqkvT, 1024, qbuf, kbuf, vbuf, 1024,
        nullptr, 0, nullptr, 0, M, 1024, flag);

    attn_kernel<<<attng, blk, 0, stream>>>(qbuf, kbuf, vbuf, Abuf);

    // Wo: 128x64 tile -> 512 blocks = 2/CU
    gemm_tt<1, 0, 64, 32><<<dim3(32, 16), blk, 0, stream>>>(
        Abuf, 1024, WoT, 1024, kbuf, nullptr, nullptr, 1024,
        nullptr, 0, x, 1024, M, 1024, flag);

    // LN2 wave-per-row: 1024 blocks x 4 rows
    ln_kernel<<<dim3(M / 4), blk, 0, stream>>>(kbuf, ln2_g, ln2_b, Abuf, 0, flag);

    // FF1: 128x64 tile -> 1024 blocks = 4/CU (r12: NT=128@2/CU lost 14.5us)
    gemm_tt<2, 0, 64, 32><<<dim3(32, 32), blk, 0, stream>>>(
        Abuf, 1024, W1T, 1024, act, nullptr, nullptr, 2048,
        b1, 0, nullptr, 0, M, 1024, flag);
    // FF2: 128x64 tile -> 512 blocks = 2/CU
    gemm_tt<5, 0, 64, 32><<<dim3(32, 16), blk, 0, stream>>>(
        act, 2048, W2T, 2048, d_out, nullptr, nullptr, 1024,
        b2, 0, kbuf, 1024, M, 2048, flag);
  } else {
    uint* flag = (uint*)(W + 12 * MEG);
    detect_dtype<<<1, 256, 0, stream>>>((const ushort*)x, flag);
    ln_kernel<<<dim3(M / 4), blk, 0, stream>>>(x, ln1_g, ln1_b, Abuf, 1, flag);
    gemm_kn<0, 0><<<g18, blk, 0, stream>>>(Abuf, 1024, Wq, 1024, 0, qbuf, 1024,
                                           nullptr, 0, nullptr, 0, M, 1024, flag);
    gemm_kn<0, 0><<<g18, blk, 0, stream>>>(Abuf, 1024, Wk, 1024, 0, kbuf, 1024,
                                           nullptr, 0, nullptr, 0, M, 1024, flag);
    gemm_kn<0, 0><<<g18, blk, 0, stream>>>(Abuf, 1024, Wv, 1024, 0, vbuf, 1024,
                                           nullptr, 0, nullptr, 0, M, 1024, flag);
    attn_kernel<<<attng, blk, 0, stream>>>(qbuf, kbuf, vbuf, Abuf);
    gemm_kn<1, 0><<<g18, blk, 0, stream>>>(Abuf, 1024, Wo, 1024, 0, kbuf, 1024,
                                           nullptr, 0, x, 1024, M, 1024, flag);
    ln_kernel<<<dim3(M / 4), blk, 0, stream>>>(kbuf, ln2_g, ln2_b, Abuf, 0, flag);
    gemm_kn<2, 0><<<g18, blk, 0, stream>>>(Abuf, 1024, W1, 2048, 0, vbuf, 1024,
                                           b1, 0, nullptr, 0, M, 1024, flag);
    gemm_kn<0, 1><<<g18, blk, 0, stream>>>(vbuf, 1024, W2, 1024, 0, d_out, 1024,
                                           nullptr, 0, nullptr, 0, M, 1024, flag);
    gemm_kn<2, 0><<<g18, blk, 0, stream>>>(Abuf, 1024, W1, 2048, 1024, vbuf, 1024,
                                           b1, 1024, nullptr, 0, M, 1024, flag);
    gemm_kn<4, 1><<<g18, blk, 0, stream>>>(vbuf, 1024, W2, 1024, (size_t)1024 * 1024,
                                           d_out, 1024, b2, 0, kbuf, 1024, M, 1024, flag);
  }
}

// Round 17
// 346.391 us; speedup vs baseline: 1.0524x; 1.0524x over previous
//
#include <hip/hip_runtime.h>
#include <hip/hip_bf16.h>

typedef __attribute__((ext_vector_type(8))) short short8;
typedef __attribute__((ext_vector_type(4))) float floatx4;
typedef __attribute__((ext_vector_type(4))) unsigned int uintx4;

#define D_MODEL 1024
#define T_SEQ   2048
#define N_HEAD  16
#define NEG_BIG (-1e30f)
#define LDSP 40 // fallback-gemm pitch
#define VP 72   // V-tile pitch: 144B rows, 16B-aligned -> true ds_read_b128
#define PP 72   // P-tile pitch
#define RESCALE_THR 8.0f  // T13 defer-max threshold (P bounded by e^8)

static __device__ __forceinline__ float bf2f(ushort u) {
  unsigned int x = ((unsigned int)u) << 16;
  return __builtin_bit_cast(float, x);
}
static __device__ __forceinline__ ushort san(ushort u) {
  return ((u & 0x7F80u) == 0x7F80u) ? (ushort)0 : u;
}
static __device__ __forceinline__ float bf2f_s(ushort u) { return bf2f(san(u)); }
static __device__ __forceinline__ ushort f2bf(float f) {
  unsigned int x = __builtin_bit_cast(unsigned int, f);
  x += 0x7FFFu + ((x >> 16) & 1u);
  return (ushort)(x >> 16);
}
static __device__ __forceinline__ float ext_ld(const void* p, size_t i, int isbf) {
  return isbf ? bf2f_s(((const ushort*)p)[i]) : ((const float*)p)[i];
}
// exact bf16 *0.125: decrement exponent by 3 (power-of-2 -> lossless).
static __device__ __forceinline__ short8 qscale8(short8 v) {
  short8 o;
#pragma unroll
  for (int i = 0; i < 8; i++) {
    ushort u = (ushort)v[i];
    int e = (u >> 7) & 0xFF;
    o[i] = (short)((e > 3) ? (ushort)(u - (3 << 7)) : (ushort)(u & 0x8000u));
  }
  return o;
}
// async global->LDS DMA, 16 B/lane; LDS dest = wave-uniform base + lane*16
static __device__ __forceinline__ void gload16(const void* g, void* l) {
  __builtin_amdgcn_global_load_lds(
      (const __attribute__((address_space(1))) void*)g,
      (__attribute__((address_space(3))) void*)l, 16, 0, 0);
}
// block barrier WITHOUT vmcnt drain (r12: attn 99.3->98.0us vs __syncthreads)
static __device__ __forceinline__ void barrier_lds_only() {
  asm volatile("s_waitcnt lgkmcnt(0)" ::: "memory");
  __builtin_amdgcn_s_barrier();
  __builtin_amdgcn_sched_barrier(0);
}

// dtype probe: low ushort of dword -> bf16 data has exp in [0x60,0x8F] ~100%
__global__ void detect_dtype(const ushort* x, uint* flag) {
  int tid = threadIdx.x;
  int cnt = 0;
  for (int j = 0; j < 16; j++) {
    ushort u = x[2 * (tid * 16 + j)];
    int e = (u >> 7) & 0xFF;
    if (e >= 0x60 && e <= 0x8F) cnt++;
  }
  for (int d = 32; d; d >>= 1) cnt += __shfl_xor(cnt, d, 64);
  __shared__ int c[4];
  if ((tid & 63) == 0) c[tid >> 6] = cnt;
  __syncthreads();
  if (tid == 0) flag[0] = (c[0] + c[1] + c[2] + c[3] >= 2048) ? 1u : 0u;
}

// prep_all: weight convert+transpose in 64x64 tiles + LN1 rows (256-thr
// block LN, r15-proven; r16's wave-per-row LN + inline probe regressed +20us).
// Blocks: 0..1023 Wq/Wk/Wv/Wo, 1024..1535 W1, 1536..2047 W2, 2048..6143 LN1.
__global__ __launch_bounds__(256) void prep_all(
    const void* __restrict__ Wq, const void* __restrict__ Wk,
    const void* __restrict__ Wv, const void* __restrict__ Wo,
    const void* __restrict__ W1, const void* __restrict__ W2,
    ushort* __restrict__ oq, ushort* __restrict__ ok, ushort* __restrict__ ov,
    ushort* __restrict__ oo, ushort* __restrict__ o1, ushort* __restrict__ o2,
    const void* __restrict__ x, const void* __restrict__ ln_g,
    const void* __restrict__ ln_b, ushort* __restrict__ ln_out,
    const uint* __restrict__ flagp) {
  int isbf = (int)*flagp;
  int id = blockIdx.x;
  int tid = threadIdx.x;

  if (id >= 2048) {
    // ---- LN1 row (ext input: dtype follows flag) ----
    int row = id - 2048;
    size_t ro = (size_t)row * D_MODEL;
    float v[4], gv[4], bv[4];
    if (!isbf) {
      floatx4 xv = *((const floatx4*)((const float*)x + ro) + tid);
#pragma unroll
      for (int i = 0; i < 4; i++) v[i] = xv[i];
    } else {
#pragma unroll
      for (int i = 0; i < 4; i++) v[i] = bf2f_s(((const ushort*)x)[ro + tid * 4 + i]);
    }
    float s = 0.f, sq = 0.f;
#pragma unroll
    for (int i = 0; i < 4; i++) { s += v[i]; sq += v[i] * v[i]; }
#pragma unroll
    for (int d = 32; d; d >>= 1) {
      s += __shfl_xor(s, d, 64);
      sq += __shfl_xor(sq, d, 64);
    }
    __shared__ float red[8];
    int wave = tid >> 6, lane = tid & 63;
    if (lane == 0) { red[wave] = s; red[4 + wave] = sq; }
    __syncthreads();
    s = red[0] + red[1] + red[2] + red[3];
    sq = red[4] + red[5] + red[6] + red[7];
    float mu = s * (1.0f / D_MODEL);
    float var = sq * (1.0f / D_MODEL) - mu * mu;
    float rs = rsqrtf(fmaxf(var, 0.f) + 1e-5f);
    if (!isbf) {
      floatx4 g4 = *((const floatx4*)ln_g + tid);
      floatx4 b4 = *((const floatx4*)ln_b + tid);
#pragma unroll
      for (int i = 0; i < 4; i++) { gv[i] = g4[i]; bv[i] = b4[i]; }
    } else {
#pragma unroll
      for (int i = 0; i < 4; i++) {
        gv[i] = bf2f_s(((const ushort*)ln_g)[tid * 4 + i]);
        bv[i] = bf2f_s(((const ushort*)ln_b)[tid * 4 + i]);
      }
    }
    ushort o4[4];
#pragma unroll
    for (int i = 0; i < 4; i++) o4[i] = f2bf((v[i] - mu) * rs * gv[i] + bv[i]);
    *(uint2*)(ln_out + ro + tid * 4) = *(uint2*)o4;
    return;
  }

  // ---- weight convert+transpose tile (64x64) ----
  const void* in;
  ushort* out;
  int R, C, local;
  if (id < 1024) {
    int w = id >> 8;
    local = id & 255;
    R = 1024; C = 1024;
    in  = (w == 0) ? Wq : (w == 1) ? Wk : (w == 2) ? Wv : Wo;
    out = (w == 0) ? oq : (w == 1) ? ok : (w == 2) ? ov : oo;
  } else if (id < 1536) {
    local = id - 1024; R = 1024; C = 2048; in = W1; out = o1;
  } else {
    local = id - 1536; R = 2048; C = 1024; in = W2; out = o2;
  }
  int cb = C >> 6;
  int c0 = (local % cb) * 64, r0 = (local / cb) * 64;
  __shared__ float t[64][65];
  int cc = tid & 63, ty = tid >> 6;
  for (int rr = ty; rr < 64; rr += 4)
    t[rr][cc] = ext_ld(in, (size_t)(r0 + rr) * C + c0 + cc, isbf);
  __syncthreads();
  for (int i = ty; i < 64; i += 4)
    out[(size_t)(c0 + i) * R + r0 + cc] = f2bf(t[cc][i]);
}

// ---------------- LayerNorm -> bf16 (LN2 only now) ----------------
__global__ __launch_bounds__(256) void ln_kernel(
    const void* __restrict__ x, const void* __restrict__ g,
    const void* __restrict__ bb, ushort* __restrict__ out,
    int ext, const uint* __restrict__ flagp) {
  int wbf = (int)*flagp;
  int xbf = ext ? wbf : 1;
  int row = blockIdx.x, tid = threadIdx.x;
  size_t ro = (size_t)row * D_MODEL;
  float v[4], gv[4], bv[4];
  if (!xbf) {
    floatx4 xv = *((const floatx4*)((const float*)x + ro) + tid);
#pragma unroll
    for (int i = 0; i < 4; i++) v[i] = xv[i];
  } else {
#pragma unroll
    for (int i = 0; i < 4; i++) v[i] = bf2f_s(((const ushort*)x)[ro + tid * 4 + i]);
  }
  float s = 0.f, sq = 0.f;
#pragma unroll
  for (int i = 0; i < 4; i++) { s += v[i]; sq += v[i] * v[i]; }
#pragma unroll
  for (int d = 32; d; d >>= 1) {
    s += __shfl_xor(s, d, 64);
    sq += __shfl_xor(sq, d, 64);
  }
  __shared__ float red[8];
  int wave = tid >> 6, lane = tid & 63;
  if (lane == 0) { red[wave] = s; red[4 + wave] = sq; }
  __syncthreads();
  s = red[0] + red[1] + red[2] + red[3];
  sq = red[4] + red[5] + red[6] + red[7];
  float mu = s * (1.0f / D_MODEL);
  float var = sq * (1.0f / D_MODEL) - mu * mu;
  float rs = rsqrtf(fmaxf(var, 0.f) + 1e-5f);
  if (!wbf) {
    floatx4 g4 = *((const floatx4*)g + tid);
    floatx4 b4 = *((const floatx4*)bb + tid);
#pragma unroll
    for (int i = 0; i < 4; i++) { gv[i] = g4[i]; bv[i] = b4[i]; }
  } else {
#pragma unroll
    for (int i = 0; i < 4; i++) {
      gv[i] = bf2f_s(((const ushort*)g)[tid * 4 + i]);
      bv[i] = bf2f_s(((const ushort*)bb)[tid * 4 + i]);
    }
  }
  ushort o4[4];
#pragma unroll
  for (int i = 0; i < 4; i++) o4[i] = f2bf((v[i] - mu) * rs * gv[i] + bv[i]);
  *(uint2*)(out + ro + tid * 4) = *(uint2*)o4;
}

// ---------------- fast GEMM: C = A[M,K] @ Bt[N,K]^T, both bf16 --------------
// EPI: 0 plain bf16 | 1 +res(ext) bf16 | 2 +bias(ext)+GELU bf16 |
//      5 +bias(ext)+res(bf16) -> store FINAL dtype
// NT: QKV=128@3/CU (r10: NT=64@6/CU regressed). Wo/FF1/FF2=64 (r4/r12).
// KSTEP=32 (r8's 64 regressed, m132-class).
template <int EPI, int SPLIT, int NT, int KSTEP>
__global__ __launch_bounds__(256) void gemm_tt(
    const ushort* __restrict__ A, int lda,
    const ushort* __restrict__ Bt, int ldbt,
    void* __restrict__ C0v, ushort* __restrict__ C1, ushort* __restrict__ C2,
    int ldc,
    const void* __restrict__ bias, size_t biasoff,
    const void* __restrict__ res, int ldr,
    int M, int K, const uint* __restrict__ flagp) {
  __shared__ __align__(16) ushort As[128 * KSTEP];
  __shared__ __align__(16) ushort Bs[NT * KSTEP];
  int isbf = (int)*flagp;
  int tid = threadIdx.x;
  int wave = tid >> 6, lane = tid & 63, lm = lane & 15, quad = lane >> 4;
  int m0 = blockIdx.x * 128, n0 = blockIdx.y * NT;
  constexpr int MR = (NT == 128) ? 4 : 2;
  constexpr int RPW = 512 / KSTEP;   // rows per wave-DMA
  constexpr int RPC = 4 * RPW;       // rows per gload16 call (4 waves)
  constexpr int LPR = KSTEP / 8;     // lanes per row
  int wm = (NT == 128) ? (wave >> 1) * 64 : wave * 32;
  int wn = (NT == 128) ? (wave & 1) * 64 : 0;
  floatx4 acc[MR][4] = {};
  int srl = lane / LPR;
  int scl = (lane % LPR) * 8;

  for (int kk = 0; kk < K; kk += KSTEP) {
#pragma unroll
    for (int i = 0; i < 128 / RPC; i++)
      gload16(A + (size_t)(m0 + i * RPC + wave * RPW + srl) * lda + kk + scl,
              &As[(i * RPC + wave * RPW) * KSTEP]);
#pragma unroll
    for (int i = 0; i < NT / RPC; i++)
      gload16(Bt + (size_t)(n0 + i * RPC + wave * RPW + srl) * ldbt + kk + scl,
              &Bs[(i * RPC + wave * RPW) * KSTEP]);
    __syncthreads();
#pragma unroll
    for (int kk2 = 0; kk2 < KSTEP; kk2 += 32) {
      short8 af[MR], bf[4];
#pragma unroll
      for (int i = 0; i < MR; i++)
        af[i] = *(const short8*)&As[(wm + i * 16 + lm) * KSTEP + kk2 + quad * 8];
#pragma unroll
      for (int i = 0; i < 4; i++)
        bf[i] = *(const short8*)&Bs[(wn + i * 16 + lm) * KSTEP + kk2 + quad * 8];
#pragma unroll
      for (int mi = 0; mi < MR; mi++)
#pragma unroll
        for (int ni = 0; ni < 4; ni++)
          acc[mi][ni] = __builtin_amdgcn_mfma_f32_16x16x32_bf16(
              af[mi], bf[ni], acc[mi][ni], 0, 0, 0);
    }
    __syncthreads();
  }

  ushort* Cseg = (ushort*)C0v;
  int colbase = n0;
  if (SPLIT) {
    int seg = n0 >> 10;
    Cseg = (seg == 0) ? (ushort*)C0v : (seg == 1 ? C1 : C2);
    colbase = n0 & 1023;
  }
#pragma unroll
  for (int mi = 0; mi < MR; mi++) {
#pragma unroll
    for (int ni = 0; ni < 4; ni++) {
      int col = colbase + wn + ni * 16 + lm;
#pragma unroll
      for (int r = 0; r < 4; r++) {
        int row = m0 + wm + mi * 16 + quad * 4 + r;
        size_t ci = (size_t)row * ldc + col;
        float v = acc[mi][ni][r];
        if (EPI == 2 || EPI == 5) v += ext_ld(bias, biasoff + col, isbf);
        if (EPI == 1) v += ext_ld(res, (size_t)row * ldr + col, isbf);
        if (EPI == 5) v += bf2f(((const ushort*)res)[(size_t)row * ldr + col]);
        if (EPI == 2) v = 0.5f * v * (1.0f + erff(v * 0.70710678118654752f));
        if (EPI == 5 && !isbf) ((float*)C0v)[ci] = v;
        else                   Cseg[ci] = f2bf(v);
      }
    }
  }
}

// ---------------- fallback GEMM: B in [K,N] external dtype ------------------
template <int EPI, int FINAL>
__global__ __launch_bounds__(256) void gemm_kn(
    const ushort* __restrict__ A, int lda,
    const void* __restrict__ B, int ldb, size_t boff,
    void* __restrict__ C, int ldc,
    const void* __restrict__ bias, size_t biasoff,
    const void* __restrict__ res, int ldr,
    int M, int K, const uint* __restrict__ flagp) {
  __shared__ __align__(16) ushort As[128 * LDSP];
  __shared__ __align__(16) ushort Bs[128 * LDSP];
  int isbf = (int)*flagp;
  int tid = threadIdx.x;
  int wave = tid >> 6, lane = tid & 63, lm = lane & 15, quad = lane >> 4;
  int m0 = blockIdx.x * 128, n0 = blockIdx.y * 128;
  int wm = (wave >> 1) * 64, wn = (wave & 1) * 64;
  floatx4 acc[4][4] = {};
  int sr = tid >> 2;
  int sc = (tid & 3) * 8;
  int bk = tid >> 4;
  int bn8 = (tid & 15) * 8;

  for (int kk = 0; kk < K; kk += 32) {
    uintx4 va0 = *(const uintx4*)(A + (size_t)(m0 + sr) * lda + kk + sc);
    uintx4 va1 = *(const uintx4*)(A + (size_t)(m0 + sr + 64) * lda + kk + sc);
    *(uintx4*)&As[sr * LDSP + sc] = va0;
    *(uintx4*)&As[(sr + 64) * LDSP + sc] = va1;
    if (isbf) {
      const ushort* Bu = (const ushort*)B;
#pragma unroll
      for (int p = 0; p < 2; p++) {
        int krow = bk + p * 16;
        uintx4 raw = *(const uintx4*)(Bu + boff + (size_t)(kk + krow) * ldb + n0 + bn8);
        ushort tmp[8] __attribute__((aligned(16)));
        *(uintx4*)tmp = raw;
#pragma unroll
        for (int i = 0; i < 8; i++) Bs[(bn8 + i) * LDSP + krow] = san(tmp[i]);
      }
    } else {
      const float* Bf = (const float*)B;
#pragma unroll
      for (int p = 0; p < 2; p++) {
        int krow = bk + p * 16;
        const float* src = Bf + boff + (size_t)(kk + krow) * ldb + n0 + bn8;
        floatx4 f0 = *(const floatx4*)src;
        floatx4 f1 = *(const floatx4*)(src + 4);
#pragma unroll
        for (int i = 0; i < 4; i++) {
          Bs[(bn8 + i) * LDSP + krow] = f2bf(f0[i]);
          Bs[(bn8 + 4 + i) * LDSP + krow] = f2bf(f1[i]);
        }
      }
    }
    __syncthreads();
    short8 af[4], bf[4];
#pragma unroll
    for (int i = 0; i < 4; i++)
      af[i] = *(const short8*)&As[(wm + i * 16 + lm) * LDSP + quad * 8];
#pragma unroll
    for (int i = 0; i < 4; i++)
      bf[i] = *(const short8*)&Bs[(wn + i * 16 + lm) * LDSP + quad * 8];
#pragma unroll
    for (int mi = 0; mi < 4; mi++)
#pragma unroll
      for (int ni = 0; ni < 4; ni++)
        acc[mi][ni] = __builtin_amdgcn_mfma_f32_16x16x32_bf16(
            af[mi], bf[ni], acc[mi][ni], 0, 0, 0);
    __syncthreads();
  }

#pragma unroll
  for (int mi = 0; mi < 4; mi++) {
#pragma unroll
    for (int ni = 0; ni < 4; ni++) {
      int col = n0 + wn + ni * 16 + lm;
#pragma unroll
      for (int r = 0; r < 4; r++) {
        int row = m0 + wm + mi * 16 + quad * 4 + r;
        size_t ci = (size_t)row * ldc + col;
        float v = acc[mi][ni][r];
        if (EPI == 4)
          v += (FINAL && !isbf) ? ((const float*)C)[ci] : bf2f(((const ushort*)C)[ci]);
        if (EPI == 2 || EPI == 4) v += ext_ld(bias, biasoff + col, isbf);
        if (EPI == 1) v += ext_ld(res, (size_t)row * ldr + col, isbf);
        if (EPI == 4) v += bf2f(((const ushort*)res)[(size_t)row * ldr + col]);
        if (EPI == 2) v = 0.5f * v * (1.0f + erff(v * 0.70710678118654752f));
        if (FINAL && !isbf) ((float*)C)[ci] = v;
        else                ((ushort*)C)[ci] = f2bf(v);
      }
    }
  }
}

// ---------------- causal flash attention (session best: 90.0us) -------------
// r15 final: uniform pairing + swapped softmax + qscale + hoisted mask +
// T13 defer-max + barrier_lds_only. DO NOT touch.
__global__ __launch_bounds__(256) void attn_kernel(
    const ushort* __restrict__ q, const ushort* __restrict__ k,
    const ushort* __restrict__ v, ushort* __restrict__ ctx) {
  int tid = threadIdx.x, wave = tid >> 6, lane = tid & 63;
  int lm = lane & 15, quad = lane >> 4;
  int bx = blockIdx.x, h = blockIdx.y, b = blockIdx.z;
  size_t base = (size_t)b * T_SEQ * D_MODEL + h * 64;

  __shared__ __align__(16) ushort Vst[64 * VP];      // [hd][key]
  __shared__ __align__(16) ushort PlAll[4][16 * PP]; // per-wave P
  ushort* Pl = PlAll[wave];

  int vr_r = tid & 63, vcg = (tid >> 6) * 16;
  const ushort* vrow = v + base + vcg;

#pragma unroll
  for (int qsel = 0; qsel < 2; ++qsel) {
    int qt = qsel ? (31 - bx) : bx;
    int qw = qt * 64 + wave * 16;

    short8 aq0 = qscale8(*(const short8*)&q[base + (size_t)(qw + lm) * D_MODEL + quad * 8]);
    short8 aq1 = qscale8(*(const short8*)&q[base + (size_t)(qw + lm) * D_MODEL + 32 + quad * 8]);

    floatx4 O[4] = {};
    float mrq = NEG_BIG, lrq = 0.f;  // running max/denom for query qw+lm

    int ntiles = qt + 1;

    // prefetch tile 0
    uintx4 vv0 = *(const uintx4*)(vrow + (size_t)vr_r * D_MODEL);
    uintx4 vv1 = *(const uintx4*)(vrow + (size_t)vr_r * D_MODEL + 8);
    short8 kfa[4], kfb[4];
#pragma unroll
    for (int g = 0; g < 4; g++) {
      const ushort* kr = &k[base + (size_t)(g * 16 + lm) * D_MODEL + quad * 8];
      kfa[g] = *(const short8*)kr;
      kfb[g] = *(const short8*)(kr + 32);
    }

    for (int kt = 0; kt < ntiles; ++kt) {
      int k0 = kt * 64;
      // scatter prefetched V into shared Vst (all 256 threads)
      {
        ushort t0[8] __attribute__((aligned(16)));
        ushort t1[8] __attribute__((aligned(16)));
        *(uintx4*)t0 = vv0;
        *(uintx4*)t1 = vv1;
#pragma unroll
        for (int i = 0; i < 8; i++) {
          Vst[(vcg + i) * VP + vr_r] = t0[i];
          Vst[(vcg + 8 + i) * VP + vr_r] = t1[i];
        }
      }
      // QK^T SWAPPED: sc[g] = S^T[key=g*16+quad*4+r][query=lm] (pre-scaled)
      floatx4 sc[4];
#pragma unroll
      for (int g = 0; g < 4; g++) {
        floatx4 z = {};
        sc[g] = __builtin_amdgcn_mfma_f32_16x16x32_bf16(kfa[g], aq0, z, 0, 0, 0);
        sc[g] = __builtin_amdgcn_mfma_f32_16x16x32_bf16(kfb[g], aq1, sc[g], 0, 0, 0);
      }
      // issue prefetch for next tile (stays in flight across barriers)
      int k0n = (kt + 1 < ntiles) ? k0 + 64 : k0;
      uintx4 nv0 = *(const uintx4*)(vrow + (size_t)(k0n + vr_r) * D_MODEL);
      uintx4 nv1 = *(const uintx4*)(vrow + (size_t)(k0n + vr_r) * D_MODEL + 8);
      short8 nka[4], nkb[4];
#pragma unroll
      for (int g = 0; g < 4; g++) {
        const ushort* kr = &k[base + (size_t)(k0n + g * 16 + lm) * D_MODEL + quad * 8];
        nka[g] = *(const short8*)kr;
        nkb[g] = *(const short8*)(kr + 32);
      }
      // online softmax: lane owns query qw+lm, 16 keys in-lane.
      bool full = (k0 + 63 <= qw);
      float a[16];
      if (full) {
#pragma unroll
        for (int g = 0; g < 4; g++)
#pragma unroll
          for (int r = 0; r < 4; r++) a[g * 4 + r] = sc[g][r];
      } else {
        int qrow = qw + lm;
#pragma unroll
        for (int g = 0; g < 4; g++)
#pragma unroll
          for (int r = 0; r < 4; r++) {
            float s = sc[g][r];
            if (k0 + g * 16 + quad * 4 + r > qrow) s = NEG_BIG;
            a[g * 4 + r] = s;
          }
      }
      float m0 = fmaxf(fmaxf(a[0], a[1]), fmaxf(a[2], a[3]));
      float m1 = fmaxf(fmaxf(a[4], a[5]), fmaxf(a[6], a[7]));
      float m2 = fmaxf(fmaxf(a[8], a[9]), fmaxf(a[10], a[11]));
      float m3 = fmaxf(fmaxf(a[12], a[13]), fmaxf(a[14], a[15]));
      float lmax = fmaxf(fmaxf(m0, m1), fmaxf(m2, m3));
      // T13 defer-max (mrq replicated across the 4 lanes of each query)
      if (!__all(lmax - mrq <= RESCALE_THR)) {
        float tm = fmaxf(lmax, __shfl_xor(lmax, 16, 64));
        tm = fmaxf(tm, __shfl_xor(tm, 32, 64));
        float mn = fmaxf(mrq, tm);
        float alpha = __expf(mrq - mn);
        mrq = mn;
        lrq *= alpha;
#pragma unroll
        for (int r = 0; r < 4; r++) {
          float aw = __shfl(alpha, quad * 4 + r, 64);
          O[0][r] *= aw; O[1][r] *= aw; O[2][r] *= aw; O[3][r] *= aw;
        }
      }
      float rs0 = 0.f, rs1 = 0.f;
#pragma unroll
      for (int i = 0; i < 8; i++) { a[i] = __expf(a[i] - mrq); rs0 += a[i]; }
#pragma unroll
      for (int i = 8; i < 16; i++) { a[i] = __expf(a[i] - mrq); rs1 += a[i]; }
      float rsum = rs0 + rs1;
      rsum += __shfl_xor(rsum, 16, 64);
      rsum += __shfl_xor(rsum, 32, 64);
      lrq += rsum;
      // P write: lane's 4 consecutive keys per g -> one ds_write_b64
#pragma unroll
      for (int g = 0; g < 4; g++) {
        ushort o4[4] __attribute__((aligned(8)));
#pragma unroll
        for (int r = 0; r < 4; r++) o4[r] = f2bf(a[g * 4 + r]);
        *(uint2*)&Pl[lm * PP + g * 16 + quad * 4] = *(uint2*)o4;
      }
      barrier_lds_only();   // Vst scatter + P stores visible; vmem in flight
      short8 pa0 = *(const short8*)&Pl[lm * PP + quad * 8];
      short8 pa1 = *(const short8*)&Pl[lm * PP + 32 + quad * 8];
#pragma unroll
      for (int d4 = 0; d4 < 4; d4++) {
        short8 bv0 = *(const short8*)&Vst[(d4 * 16 + lm) * VP + quad * 8];
        short8 bv1 = *(const short8*)&Vst[(d4 * 16 + lm) * VP + 32 + quad * 8];
        O[d4] = __builtin_amdgcn_mfma_f32_16x16x32_bf16(pa0, bv0, O[d4], 0, 0, 0);
        O[d4] = __builtin_amdgcn_mfma_f32_16x16x32_bf16(pa1, bv1, O[d4], 0, 0, 0);
      }
      barrier_lds_only();   // all waves' Vst/Pl reads drained (lgkm) -> WAR safe
      vv0 = nv0; vv1 = nv1;
#pragma unroll
      for (int g = 0; g < 4; g++) { kfa[g] = nka[g]; kfb[g] = nkb[g]; }
    }
    float linv = 1.0f / fmaxf(lrq, 1e-20f);
#pragma unroll
    for (int r = 0; r < 4; r++) {
      float lw = __shfl(linv, quad * 4 + r, 64);
#pragma unroll
      for (int d4 = 0; d4 < 4; d4++) {
        ctx[base + (size_t)(qw + quad * 4 + r) * D_MODEL + d4 * 16 + lm] =
            f2bf(O[d4][r] * lw);
      }
    }
  }
}

// ---------------------------------------------------------------------------
extern "C" void kernel_launch(void* const* d_in, const int* in_sizes, int n_in,
                              void* d_out, int out_size, void* d_ws, size_t ws_size,
                              hipStream_t stream) {
  const void* x     = d_in[0];
  const void* ln1_g = d_in[1];
  const void* ln1_b = d_in[2];
  const void* Wq    = d_in[3];
  const void* Wk    = d_in[4];
  const void* Wv    = d_in[5];
  const void* Wo    = d_in[6];
  const void* ln2_g = d_in[7];
  const void* ln2_b = d_in[8];
  const void* W1    = d_in[9];
  const void* b1    = d_in[10];
  const void* W2    = d_in[11];
  const void* b2    = d_in[12];

  const int M = 2 * T_SEQ;  // 4096
  const size_t MEG = 1024 * 1024;
  ushort* W = (ushort*)d_ws;
  ushort* Abuf = W;             // h1 -> ctx -> h2
  ushort* kbuf = W + 4 * MEG;   // k -> x2
  ushort* vbuf = W + 8 * MEG;   // v row-major
  ushort* qbuf = (ushort*)d_out;

  dim3 blk(256);
  dim3 g18(32, 8);
  dim3 attng(T_SEQ / 128, N_HEAD, 2);  // 16 q-tile PAIRS x 16 heads x 2 batch

  bool fast = ws_size >= (size_t)40 * MEG + 4096;

  if (fast) {
    ushort* WqkvT = W + 12 * MEG;             // dead after QKV
    ushort* WoT   = W + 15 * MEG;             // dead after Wo
    ushort* W1T   = W + 16 * MEG;
    ushort* W2T   = W + 18 * MEG;
    ushort* act   = W + 8 * MEG;              // [4096,2048] over v/WqkvT/WoT
    uint* flag = (uint*)(W + 20 * MEG);

    detect_dtype<<<1, 256, 0, stream>>>((const ushort*)x, flag);

    // wconv 64x64 tiles (2048 blocks) + LN1 (4096 blocks) in one launch
    prep_all<<<dim3(6144), blk, 0, stream>>>(
        Wq, Wk, Wv, Wo, W1, W2,
        WqkvT, WqkvT + 1 * MEG, WqkvT + 2 * MEG, WoT, W1T, W2T,
        x, ln1_g, ln1_b, Abuf, flag);

    // QKV: 128x128 tile, KSTEP=32 (768 blocks = 3/CU)
    gemm_tt<0, 1, 128, 32><<<dim3(32, 24), blk, 0, stream>>>(
        Abuf, 1024, WqkvT, 1024, qbuf, kbuf, vbuf, 1024,
        nullptr, 0, nullptr, 0, M, 1024, flag);

    attn_kernel<<<attng, blk, 0, stream>>>(qbuf, kbuf, vbuf, Abuf);

    // Wo: 128x64 tile -> 512 blocks = 2/CU
    gemm_tt<1, 0, 64, 32><<<dim3(32, 16), blk, 0, stream>>>(
        Abuf, 1024, WoT, 1024, kbuf, nullptr, nullptr, 1024,
        nullptr, 0, x, 1024, M, 1024, flag);

    ln_kernel<<<dim3(M), blk, 0, stream>>>(kbuf, ln2_g, ln2_b, Abuf, 0, flag);

    // FF1: 128x64 tile -> 1024 blocks = 4/CU (r12: NT=128@2/CU lost 14.5us)
    gemm_tt<2, 0, 64, 32><<<dim3(32, 32), blk, 0, stream>>>(
        Abuf, 1024, W1T, 1024, act, nullptr, nullptr, 2048,
        b1, 0, nullptr, 0, M, 1024, flag);
    // FF2: 128x64 tile -> 512 blocks = 2/CU
    gemm_tt<5, 0, 64, 32><<<dim3(32, 16), blk, 0, stream>>>(
        act, 2048, W2T, 2048, d_out, nullptr, nullptr, 1024,
        b2, 0, kbuf, 1024, M, 2048, flag);
  } else {
    uint* flag = (uint*)(W + 12 * MEG);
    detect_dtype<<<1, 256, 0, stream>>>((const ushort*)x, flag);
    ln_kernel<<<dim3(M), blk, 0, stream>>>(x, ln1_g, ln1_b, Abuf, 1, flag);
    gemm_kn<0, 0><<<g18, blk, 0, stream>>>(Abuf, 1024, Wq, 1024, 0, qbuf, 1024,
                                           nullptr, 0, nullptr, 0, M, 1024, flag);
    gemm_kn<0, 0><<<g18, blk, 0, stream>>>(Abuf, 1024, Wk, 1024, 0, kbuf, 1024,
                                           nullptr, 0, nullptr, 0, M, 1024, flag);
    gemm_kn<0, 0><<<g18, blk, 0, stream>>>(Abuf, 1024, Wv, 1024, 0, vbuf, 1024,
                                           nullptr, 0, nullptr, 0, M, 1024, flag);
    attn_kernel<<<attng, blk, 0, stream>>>(qbuf, kbuf, vbuf, Abuf);
    gemm_kn<1, 0><<<g18, blk, 0, stream>>>(Abuf, 1024, Wo, 1024, 0, kbuf, 1024,
                                           nullptr, 0, x, 1024, M, 1024, flag);
    ln_kernel<<<dim3(M), blk, 0, stream>>>(kbuf, ln2_g, ln2_b, Abuf, 0, flag);
    gemm_kn<2, 0><<<g18, blk, 0, stream>>>(Abuf, 1024, W1, 2048, 0, vbuf, 1024,
                                           b1, 0, nullptr, 0, M, 1024, flag);
    gemm_kn<0, 1><<<g18, blk, 0, stream>>>(vbuf, 1024, W2, 1024, 0, d_out, 1024,
                                           nullptr, 0, nullptr, 0, M, 1024, flag);
    gemm_kn<2, 0><<<g18, blk, 0, stream>>>(Abuf, 1024, W1, 2048, 1024, vbuf, 1024,
                                           b1, 1024, nullptr, 0, M, 1024, flag);
    gemm_kn<4, 1><<<g18, blk, 0, stream>>>(vbuf, 1024, W2, 1024, (size_t)1024 * 1024,
                                           d_out, 1024, b2, 0, kbuf, 1024, M, 1024, flag);
  }
}